// Round 1
// baseline (404.994 us; speedup 1.0000x reference)
//
#include <hip/hip_runtime.h>

#define M_VERT 32768
#define NBATCH 8
#define FIN 32
#define RANK 5
#define FILT 32
#define E_NNZ 262144
#define ROWLEN 256   // NBATCH*FIN floats per vertex row

// ---------------- CSR build ----------------

__global__ void hist_kernel(const int* __restrict__ rows, int* __restrict__ cnt) {
    int e = blockIdx.x * blockDim.x + threadIdx.x;
    if (e < E_NNZ) atomicAdd(&cnt[rows[e]], 1);
}

// single block, 1024 threads: exclusive prefix sum of cnt[0..M-1] -> rp[0..M];
// also re-zeroes cnt (same buffer passed as `fill`) for use as scatter cursor.
__global__ __launch_bounds__(1024) void scan_kernel(const int* __restrict__ cnt,
                                                    int* __restrict__ rp,
                                                    int* __restrict__ fill) {
    __shared__ int sums[1024];
    int t = threadIdx.x;
    int base = t * 32;
    int local[32];
    int s = 0;
#pragma unroll
    for (int i = 0; i < 32; ++i) { local[i] = cnt[base + i]; s += local[i]; }
    sums[t] = s;
    __syncthreads();
    for (int off = 1; off < 1024; off <<= 1) {
        int add = (t >= off) ? sums[t - off] : 0;
        __syncthreads();
        sums[t] += add;
        __syncthreads();
    }
    int pre = (t == 0) ? 0 : sums[t - 1];
#pragma unroll
    for (int i = 0; i < 32; ++i) { rp[base + i] = pre; pre += local[i]; }
    if (t == 1023) rp[M_VERT] = pre;   // == E_NNZ
#pragma unroll
    for (int i = 0; i < 32; ++i) fill[base + i] = 0;
}

__global__ void scatter_kernel(const int* __restrict__ rows, const int* __restrict__ cols,
                               const float* __restrict__ vals, const int* __restrict__ rp,
                               int* __restrict__ fill, int* __restrict__ cs,
                               float* __restrict__ vs) {
    int e = blockIdx.x * blockDim.x + threadIdx.x;
    if (e < E_NNZ) {
        int r = rows[e];
        int pos = rp[r] + atomicAdd(&fill[r], 1);
        cs[pos] = cols[e];
        vs[pos] = vals[e];
    }
}

// ---------------- pack x [N,M,Fin] -> T0 [M, n*32+fin] ----------------

__global__ void pack_kernel(const float* __restrict__ x, float* __restrict__ T0) {
    int tid = blockIdx.x * blockDim.x + threadIdx.x;   // 0 .. M*64-1 (float4 units)
    int m  = tid >> 6;
    int r  = tid & 63;
    int n  = r >> 3;
    int fq = r & 7;
    const float4 v = *(const float4*)(x + ((size_t)n * M_VERT + m) * FIN + fq * 4);
    *(float4*)(T0 + (size_t)m * ROWLEN + n * FIN + fq * 4) = v;
}

// ---------------- SpMM: Tout = L*Tin   or   Tout = 2*L*Tin - Tout(old) ----------------
// one wave per vertex, float4 per lane (64*4 = 256 floats)

__global__ __launch_bounds__(256) void spmm_kernel(const int* __restrict__ rp,
                                                   const int* __restrict__ cs,
                                                   const float* __restrict__ vs,
                                                   const float* __restrict__ Tin,
                                                   float* __restrict__ Tout, int cheb) {
    int w = threadIdx.x >> 6;
    int l = threadIdx.x & 63;
    int m = blockIdx.x * 4 + w;
    size_t base = (size_t)m * ROWLEN + l * 4;
    float4 acc = make_float4(0.f, 0.f, 0.f, 0.f);
    int s = rp[m], e = rp[m + 1];
    for (int j = s; j < e; ++j) {
        int c = cs[j];
        float v = vs[j];
        const float4 t = *(const float4*)(Tin + (size_t)c * ROWLEN + l * 4);
        acc.x += v * t.x; acc.y += v * t.y; acc.z += v * t.z; acc.w += v * t.w;
    }
    float4* outp = (float4*)(Tout + base);
    if (cheb) {
        float4 old = *outp;
        acc.x = 2.f * acc.x - old.x;
        acc.y = 2.f * acc.y - old.y;
        acc.z = 2.f * acc.z - old.z;
        acc.w = 2.f * acc.w - old.w;
    }
    *outp = acc;
}

// ---------------- epilogue: out (+)= T_k @ W_k (+ bias at k==0) ----------------
// block = 256 threads handles 128 (m) rows x 32 filts for one batch n.
// 4x4 register tile per thread; A (T, transposed) and B (W_k) from LDS via b128.

#define SP 132   // LDS stride for transposed T tile (128 + 4 pad, 16B-aligned rows)

__global__ __launch_bounds__(256) void accum_kernel(const float* __restrict__ T,
                                                    const float* __restrict__ W,
                                                    const float* __restrict__ bias,
                                                    float* __restrict__ out, int k) {
    __shared__ float Tl[32 * SP];    // [fin][m-local]
    __shared__ float Wl[32 * 32];    // [fin][filt]
    int t  = threadIdx.x;
    int b  = blockIdx.x;
    int n  = b >> 8;                 // 256 m-blocks per batch (32768/128)
    int m0 = (b & 255) * 128;

#pragma unroll
    for (int j = 0; j < 4; ++j) {    // load W_k: Wl[fin*32+f] = W[(fin*5+k)*32+f]
        int idx = j * 256 + t;
        int fin = idx >> 5, f = idx & 31;
        Wl[idx] = W[(fin * RANK + k) * FILT + f];
    }
#pragma unroll
    for (int j = 0; j < 4; ++j) {    // load T tile, transpose into LDS
        int flat = j * 256 + t;
        int i  = flat >> 3;          // 0..127 local m
        int fq = flat & 7;
        const float4 v = *(const float4*)(T + (size_t)(m0 + i) * ROWLEN + n * FIN + fq * 4);
        Tl[(fq * 4 + 0) * SP + i] = v.x;
        Tl[(fq * 4 + 1) * SP + i] = v.y;
        Tl[(fq * 4 + 2) * SP + i] = v.z;
        Tl[(fq * 4 + 3) * SP + i] = v.w;
    }
    __syncthreads();

    int tx = t & 7;                  // filt group: tx*4 .. +3
    int ty = t >> 3;                 // m group:    ty*4 .. +3
    float acc[4][4];
#pragma unroll
    for (int i = 0; i < 4; ++i)
#pragma unroll
        for (int j = 0; j < 4; ++j) acc[i][j] = 0.f;

#pragma unroll
    for (int fin = 0; fin < 32; ++fin) {
        const float4 a  = *(const float4*)&Tl[fin * SP + ty * 4];
        const float4 b4 = *(const float4*)&Wl[fin * 32 + tx * 4];
        acc[0][0] += a.x * b4.x; acc[0][1] += a.x * b4.y; acc[0][2] += a.x * b4.z; acc[0][3] += a.x * b4.w;
        acc[1][0] += a.y * b4.x; acc[1][1] += a.y * b4.y; acc[1][2] += a.y * b4.z; acc[1][3] += a.y * b4.w;
        acc[2][0] += a.z * b4.x; acc[2][1] += a.z * b4.y; acc[2][2] += a.z * b4.z; acc[2][3] += a.z * b4.w;
        acc[3][0] += a.w * b4.x; acc[3][1] += a.w * b4.y; acc[3][2] += a.w * b4.z; acc[3][3] += a.w * b4.w;
    }

    size_t ob = ((size_t)n * M_VERT + (size_t)(m0 + ty * 4)) * FILT + tx * 4;
    if (k == 0) {
        const float4 bv = *(const float4*)(bias + tx * 4);
#pragma unroll
        for (int i = 0; i < 4; ++i) {
            float4 r;
            r.x = bv.x + acc[i][0]; r.y = bv.y + acc[i][1];
            r.z = bv.z + acc[i][2]; r.w = bv.w + acc[i][3];
            *(float4*)(out + ob + (size_t)i * FILT) = r;
        }
    } else {
#pragma unroll
        for (int i = 0; i < 4; ++i) {
            float4 r = *(const float4*)(out + ob + (size_t)i * FILT);
            r.x += acc[i][0]; r.y += acc[i][1]; r.z += acc[i][2]; r.w += acc[i][3];
            *(float4*)(out + ob + (size_t)i * FILT) = r;
        }
    }
}

// ---------------- launch ----------------

extern "C" void kernel_launch(void* const* d_in, const int* in_sizes, int n_in,
                              void* d_out, int out_size, void* d_ws, size_t ws_size,
                              hipStream_t stream) {
    const float* x    = (const float*)d_in[0];
    const float* vals = (const float*)d_in[1];
    const float* W    = (const float*)d_in[2];
    const float* bias = (const float*)d_in[3];
    const int*   rows = (const int*)d_in[4];
    const int*   cols = (const int*)d_in[5];
    float* out = (float*)d_out;

    // workspace layout (~66.3 MiB)
    float* TA  = (float*)d_ws;
    float* TB  = TA + (size_t)M_VERT * ROWLEN;
    int*   rp  = (int*)(TB + (size_t)M_VERT * ROWLEN);
    int*   fill = rp + (M_VERT + 2);
    int*   cs  = fill + M_VERT;
    float* vs  = (float*)(cs + E_NNZ);

    hipMemsetAsync(fill, 0, M_VERT * sizeof(int), stream);
    hist_kernel<<<E_NNZ / 256, 256, 0, stream>>>(rows, fill);
    scan_kernel<<<1, 1024, 0, stream>>>(fill, rp, fill);
    scatter_kernel<<<E_NNZ / 256, 256, 0, stream>>>(rows, cols, vals, rp, fill, cs, vs);
    pack_kernel<<<M_VERT * 64 / 256, 256, 0, stream>>>(x, TA);

    // k=0: out = bias + T0 @ W0
    accum_kernel<<<2048, 256, 0, stream>>>(TA, W, bias, out, 0);
    // T1 = L T0
    spmm_kernel<<<M_VERT / 4, 256, 0, stream>>>(rp, cs, vs, TA, TB, 0);
    accum_kernel<<<2048, 256, 0, stream>>>(TB, W, bias, out, 1);
    // T2 = 2 L T1 - T0   (overwrites TA in place)
    spmm_kernel<<<M_VERT / 4, 256, 0, stream>>>(rp, cs, vs, TB, TA, 1);
    accum_kernel<<<2048, 256, 0, stream>>>(TA, W, bias, out, 2);
    // T3 = 2 L T2 - T1   (overwrites TB)
    spmm_kernel<<<M_VERT / 4, 256, 0, stream>>>(rp, cs, vs, TA, TB, 1);
    accum_kernel<<<2048, 256, 0, stream>>>(TB, W, bias, out, 3);
    // T4 = 2 L T3 - T2   (overwrites TA)
    spmm_kernel<<<M_VERT / 4, 256, 0, stream>>>(rp, cs, vs, TB, TA, 1);
    accum_kernel<<<2048, 256, 0, stream>>>(TA, W, bias, out, 4);
}

// Round 2
// 307.370 us; speedup vs baseline: 1.3176x; 1.3176x over previous
//
#include <hip/hip_runtime.h>

#define M_VERT 32768
#define NBATCH 8
#define FIN 32
#define RANK 5
#define FILT 32
#define E_NNZ 262144
#define ROWLEN 256   // NBATCH*FIN elements per vertex row

typedef short short8 __attribute__((ext_vector_type(8)));
typedef float f32x4 __attribute__((ext_vector_type(4)));

__device__ __forceinline__ float bfl(unsigned int u) {           // low bf16 -> f32
    unsigned int x = u << 16; return __builtin_bit_cast(float, x);
}
__device__ __forceinline__ float bfh(unsigned int u) {           // high bf16 -> f32
    unsigned int x = u & 0xffff0000u; return __builtin_bit_cast(float, x);
}
__device__ __forceinline__ unsigned int f2bf(float f) {          // f32 -> bf16 (RNE), low 16
    unsigned int x = __builtin_bit_cast(unsigned int, f);
    return (x + 0x7fffu + ((x >> 16) & 1u)) >> 16;
}
__device__ __forceinline__ unsigned int pk(float a, float b) {   // pack 2 bf16
    return f2bf(a) | (f2bf(b) << 16);
}

// ---------------- CSR build ----------------

__global__ void hist_kernel(const int* __restrict__ rows, int* __restrict__ cnt) {
    int e = blockIdx.x * blockDim.x + threadIdx.x;
    if (e < E_NNZ) atomicAdd(&cnt[rows[e]], 1);
}

__global__ __launch_bounds__(1024) void scan_kernel(const int* __restrict__ cnt,
                                                    int* __restrict__ rp,
                                                    int* __restrict__ fill) {
    __shared__ int sums[1024];
    int t = threadIdx.x;
    int base = t * 32;
    int local[32];
    int s = 0;
#pragma unroll
    for (int i = 0; i < 32; ++i) { local[i] = cnt[base + i]; s += local[i]; }
    sums[t] = s;
    __syncthreads();
    for (int off = 1; off < 1024; off <<= 1) {
        int add = (t >= off) ? sums[t - off] : 0;
        __syncthreads();
        sums[t] += add;
        __syncthreads();
    }
    int pre = (t == 0) ? 0 : sums[t - 1];
#pragma unroll
    for (int i = 0; i < 32; ++i) { rp[base + i] = pre; pre += local[i]; }
    if (t == 1023) rp[M_VERT] = pre;
#pragma unroll
    for (int i = 0; i < 32; ++i) fill[base + i] = 0;
}

__global__ void scatter_kernel(const int* __restrict__ rows, const int* __restrict__ cols,
                               const float* __restrict__ vals, const int* __restrict__ rp,
                               int* __restrict__ fill, int* __restrict__ cs,
                               float* __restrict__ vs) {
    int e = blockIdx.x * blockDim.x + threadIdx.x;
    if (e < E_NNZ) {
        int r = rows[e];
        int pos = rp[r] + atomicAdd(&fill[r], 1);
        cs[pos] = cols[e];
        vs[pos] = vals[e];
    }
}

// ---------------- pack x [N,M,Fin] fp32 -> T0 [M, n*32+fin] bf16 ----------------

__global__ void pack_kernel(const float* __restrict__ x, unsigned short* __restrict__ T0) {
    int tid = blockIdx.x * blockDim.x + threadIdx.x;   // M*32 threads, 8 elems each
    int m = tid >> 5;
    int r = tid & 31;
    int n = r >> 2;
    int q = r & 3;
    const float* src = x + ((size_t)n * M_VERT + m) * FIN + q * 8;
    float4 v0 = *(const float4*)(src);
    float4 v1 = *(const float4*)(src + 4);
    uint4 u;
    u.x = pk(v0.x, v0.y); u.y = pk(v0.z, v0.w);
    u.z = pk(v1.x, v1.y); u.w = pk(v1.z, v1.w);
    *(uint4*)(T0 + (size_t)m * ROWLEN + n * FIN + q * 8) = u;
}

// ---------------- pack W fp32 -> MFMA B-fragment layout, bf16 ----------------
// Wb[((k*2+ft)*64 + lane)*8 + j] = bf16(W[(fin*5+k)*32 + ft*16 + (lane&15)]),
// fin = (lane>>4)*8 + j   (B[k][n] frag: n=lane&15, k=quad*8+j)

__global__ void packw_kernel(const float* __restrict__ W, unsigned short* __restrict__ Wb) {
    int idx = blockIdx.x * blockDim.x + threadIdx.x;   // 640 total
    if (idx >= 640) return;
    int lane = idx & 63;
    int kf = idx >> 6;          // 0..9 = k*2+ft
    int k = kf >> 1, ft = kf & 1;
    int f = ft * 16 + (lane & 15);
    int fin0 = (lane >> 4) * 8;
    unsigned short tmp[8];
#pragma unroll
    for (int j = 0; j < 8; ++j)
        tmp[j] = (unsigned short)f2bf(W[((fin0 + j) * RANK + k) * FILT + f]);
    uint4 u;
    u.x = (unsigned int)tmp[0] | ((unsigned int)tmp[1] << 16);
    u.y = (unsigned int)tmp[2] | ((unsigned int)tmp[3] << 16);
    u.z = (unsigned int)tmp[4] | ((unsigned int)tmp[5] << 16);
    u.w = (unsigned int)tmp[6] | ((unsigned int)tmp[7] << 16);
    *(uint4*)(Wb + (size_t)idx * 8) = u;
}

// ---------------- SpMM (bf16): Tout = L*Tin  or  2*L*Tin - Tsub ----------------
// one wave per vertex; lane holds 4 bf16 columns (8 B dwordx2 gather)

__global__ __launch_bounds__(256) void spmm_kernel(const int* __restrict__ rp,
                                                   const int* __restrict__ cs,
                                                   const float* __restrict__ vs,
                                                   const unsigned short* __restrict__ Tin,
                                                   const unsigned short* __restrict__ Tsub,
                                                   unsigned short* __restrict__ Tout, int cheb) {
    int w = threadIdx.x >> 6;
    int l = threadIdx.x & 63;
    int m = blockIdx.x * 4 + w;
    int col = l * 4;
    float a0 = 0.f, a1 = 0.f, a2 = 0.f, a3 = 0.f;
    int s = rp[m], e = rp[m + 1];
    for (int j = s; j < e; ++j) {
        int c = cs[j];
        float v = vs[j];
        uint2 t = *(const uint2*)(Tin + (size_t)c * ROWLEN + col);
        a0 += v * bfl(t.x); a1 += v * bfh(t.x);
        a2 += v * bfl(t.y); a3 += v * bfh(t.y);
    }
    if (cheb) {
        uint2 o = *(const uint2*)(Tsub + (size_t)m * ROWLEN + col);
        a0 = 2.f * a0 - bfl(o.x); a1 = 2.f * a1 - bfh(o.x);
        a2 = 2.f * a2 - bfl(o.y); a3 = 2.f * a3 - bfh(o.y);
    }
    uint2 r;
    r.x = pk(a0, a1); r.y = pk(a2, a3);
    *(uint2*)(Tout + (size_t)m * ROWLEN + col) = r;
}

// ---------------- final GEMM: out[n,m,f] = bias[f] + sum_k T_k[m, n*32+:] @ W_k ----------------
// MFMA 16x16x32 bf16, A loaded straight from global (frag = 8 contiguous bf16),
// B frags preloaded once from Wb, no LDS.

__global__ __launch_bounds__(256) void gemm_kernel(const unsigned short* __restrict__ T0,
                                                   const unsigned short* __restrict__ T1,
                                                   const unsigned short* __restrict__ T2,
                                                   const unsigned short* __restrict__ T3,
                                                   const unsigned short* __restrict__ T4,
                                                   const unsigned short* __restrict__ Wb,
                                                   const float* __restrict__ bias,
                                                   float* __restrict__ out) {
    int w = threadIdx.x >> 6;
    int l = threadIdx.x & 63;
    int m0 = (blockIdx.x * 4 + w) * 16;
    int lrow = l & 15;           // A's m-offset AND C's column f
    int quad = l >> 4;

    short8 bfrag[5][2];
#pragma unroll
    for (int kf = 0; kf < 10; ++kf)
        bfrag[kf >> 1][kf & 1] = *(const short8*)(Wb + ((size_t)kf * 64 + l) * 8);

    float b0 = bias[lrow];
    float b1 = bias[16 + lrow];

    const unsigned short* Ts[5] = {T0, T1, T2, T3, T4};
    size_t abase = (size_t)(m0 + lrow) * ROWLEN + quad * 8;

#pragma unroll 1
    for (int n = 0; n < NBATCH; ++n) {
        f32x4 c0 = {0.f, 0.f, 0.f, 0.f};
        f32x4 c1 = {0.f, 0.f, 0.f, 0.f};
#pragma unroll
        for (int k = 0; k < 5; ++k) {
            short8 a = *(const short8*)(Ts[k] + abase + n * FIN);
            c0 = __builtin_amdgcn_mfma_f32_16x16x32_bf16(a, bfrag[k][0], c0, 0, 0, 0);
            c1 = __builtin_amdgcn_mfma_f32_16x16x32_bf16(a, bfrag[k][1], c1, 0, 0, 0);
        }
        float* op = out + ((size_t)n * M_VERT + m0) * FILT;
#pragma unroll
        for (int r = 0; r < 4; ++r) {
            int orow = quad * 4 + r;
            op[(size_t)orow * FILT + lrow]      = c0[r] + b0;
            op[(size_t)orow * FILT + 16 + lrow] = c1[r] + b1;
        }
    }
}

// ---------------- launch ----------------

extern "C" void kernel_launch(void* const* d_in, const int* in_sizes, int n_in,
                              void* d_out, int out_size, void* d_ws, size_t ws_size,
                              hipStream_t stream) {
    const float* x    = (const float*)d_in[0];
    const float* vals = (const float*)d_in[1];
    const float* W    = (const float*)d_in[2];
    const float* bias = (const float*)d_in[3];
    const int*   rows = (const int*)d_in[4];
    const int*   cols = (const int*)d_in[5];
    float* out = (float*)d_out;

    // workspace layout: 5 bf16 T buffers (16 MiB each) + CSR + Wb  (~87 MiB)
    const size_t TSZ = (size_t)M_VERT * ROWLEN;          // elements
    unsigned short* T0 = (unsigned short*)d_ws;
    unsigned short* T1 = T0 + TSZ;
    unsigned short* T2 = T1 + TSZ;
    unsigned short* T3 = T2 + TSZ;
    unsigned short* T4 = T3 + TSZ;
    int*   rp   = (int*)(T4 + TSZ);
    int*   fill = rp + (M_VERT + 2);
    int*   cs   = fill + M_VERT;
    float* vs   = (float*)(cs + E_NNZ);
    unsigned short* Wb = (unsigned short*)(vs + E_NNZ);  // 5*2*64*8 bf16

    hipMemsetAsync(fill, 0, M_VERT * sizeof(int), stream);
    hist_kernel<<<E_NNZ / 256, 256, 0, stream>>>(rows, fill);
    scan_kernel<<<1, 1024, 0, stream>>>(fill, rp, fill);
    scatter_kernel<<<E_NNZ / 256, 256, 0, stream>>>(rows, cols, vals, rp, fill, cs, vs);
    packw_kernel<<<3, 256, 0, stream>>>(W, Wb);
    pack_kernel<<<M_VERT * 32 / 256, 256, 0, stream>>>(x, T0);

    // Chebyshev recurrence, all T_k kept (bf16)
    spmm_kernel<<<M_VERT / 4, 256, 0, stream>>>(rp, cs, vs, T0, T0, T1, 0);
    spmm_kernel<<<M_VERT / 4, 256, 0, stream>>>(rp, cs, vs, T1, T0, T2, 1);
    spmm_kernel<<<M_VERT / 4, 256, 0, stream>>>(rp, cs, vs, T2, T1, T3, 1);
    spmm_kernel<<<M_VERT / 4, 256, 0, stream>>>(rp, cs, vs, T3, T2, T4, 1);

    // single fused epilogue GEMM
    gemm_kernel<<<M_VERT / 64, 256, 0, stream>>>(T0, T1, T2, T3, T4, Wb, bias, out);
}

// Round 3
// 264.444 us; speedup vs baseline: 1.5315x; 1.1623x over previous
//
#include <hip/hip_runtime.h>

#define M_VERT 32768
#define NBATCH 8
#define FIN 32
#define RANK 5
#define FILT 32
#define E_NNZ 262144
#define ROWLEN 256                    // NBATCH*FIN elements per vertex row
#define EPAD (E_NNZ + 7 * M_VERT)     // upper bound on 8-padded edge count

typedef short short8 __attribute__((ext_vector_type(8)));
typedef float f32x4 __attribute__((ext_vector_type(4)));

__device__ __forceinline__ float bfl(unsigned int u) {           // low bf16 -> f32
    unsigned int x = u << 16; return __builtin_bit_cast(float, x);
}
__device__ __forceinline__ float bfh(unsigned int u) {           // high bf16 -> f32
    unsigned int x = u & 0xffff0000u; return __builtin_bit_cast(float, x);
}
__device__ __forceinline__ unsigned int f2bf(float f) {          // f32 -> bf16 (RNE)
    unsigned int x = __builtin_bit_cast(unsigned int, f);
    return (x + 0x7fffu + ((x >> 16) & 1u)) >> 16;
}
__device__ __forceinline__ unsigned int pk(float a, float b) {
    return f2bf(a) | (f2bf(b) << 16);
}

// ---------------- CSR build (rows padded to multiples of 8) ----------------

__global__ void hist_kernel(const int* __restrict__ rows, int* __restrict__ cnt) {
    int e = blockIdx.x * blockDim.x + threadIdx.x;
    if (e < E_NNZ) atomicAdd(&cnt[rows[e]], 1);
}

// exclusive prefix sum of ceil8(cnt) -> rp[0..M]; re-zeroes fill cursor
__global__ __launch_bounds__(1024) void scan_kernel(const int* __restrict__ cnt,
                                                    int* __restrict__ rp,
                                                    int* __restrict__ fill) {
    __shared__ int sums[1024];
    int t = threadIdx.x;
    int base = t * 32;
    int local[32];
    int s = 0;
#pragma unroll
    for (int i = 0; i < 32; ++i) {
        int c = (cnt[base + i] + 7) & ~7;        // pad to multiple of 8
        local[i] = c; s += c;
    }
    sums[t] = s;
    __syncthreads();
    for (int off = 1; off < 1024; off <<= 1) {
        int add = (t >= off) ? sums[t - off] : 0;
        __syncthreads();
        sums[t] += add;
        __syncthreads();
    }
    int pre = (t == 0) ? 0 : sums[t - 1];
#pragma unroll
    for (int i = 0; i < 32; ++i) { rp[base + i] = pre; pre += local[i]; }
    if (t == 1023) rp[M_VERT] = pre;
#pragma unroll
    for (int i = 0; i < 32; ++i) fill[base + i] = 0;
}

__global__ void scatter_kernel(const int* __restrict__ rows, const int* __restrict__ cols,
                               const float* __restrict__ vals, const int* __restrict__ rp,
                               int* __restrict__ fill, int2* __restrict__ ev) {
    int e = blockIdx.x * blockDim.x + threadIdx.x;
    if (e < E_NNZ) {
        int r = rows[e];
        int pos = rp[r] + atomicAdd(&fill[r], 1);
        int2 p; p.x = cols[e]; p.y = __builtin_bit_cast(int, vals[e]);
        ev[pos] = p;
    }
}

// ---------------- pack x [N,M,Fin] fp32 -> T0 [M, n*32+fin] bf16 ----------------

__global__ void pack_kernel(const float* __restrict__ x, unsigned short* __restrict__ T0) {
    int tid = blockIdx.x * blockDim.x + threadIdx.x;   // M*32 threads, 8 elems each
    int m = tid >> 5;
    int r = tid & 31;
    int n = r >> 2;
    int q = r & 3;
    const float* src = x + ((size_t)n * M_VERT + m) * FIN + q * 8;
    float4 v0 = *(const float4*)(src);
    float4 v1 = *(const float4*)(src + 4);
    uint4 u;
    u.x = pk(v0.x, v0.y); u.y = pk(v0.z, v0.w);
    u.z = pk(v1.x, v1.y); u.w = pk(v1.z, v1.w);
    *(uint4*)(T0 + (size_t)m * ROWLEN + n * FIN + q * 8) = u;
}

// ---------------- pack W fp32 -> MFMA B-fragment layout, bf16 ----------------
// Wb[((k*2+ft)*64 + lane)*8 + j] = bf16(W[(fin*5+k)*32 + ft*16 + (lane&15)]),
// fin = (lane>>4)*8 + j

__global__ void packw_kernel(const float* __restrict__ W, unsigned short* __restrict__ Wb) {
    int idx = blockIdx.x * blockDim.x + threadIdx.x;   // 640 total
    if (idx >= 640) return;
    int lane = idx & 63;
    int kf = idx >> 6;
    int k = kf >> 1, ft = kf & 1;
    int f = ft * 16 + (lane & 15);
    int fin0 = (lane >> 4) * 8;
    unsigned short tmp[8];
#pragma unroll
    for (int j = 0; j < 8; ++j)
        tmp[j] = (unsigned short)f2bf(W[((fin0 + j) * RANK + k) * FILT + f]);
    uint4 u;
    u.x = (unsigned int)tmp[0] | ((unsigned int)tmp[1] << 16);
    u.y = (unsigned int)tmp[2] | ((unsigned int)tmp[3] << 16);
    u.z = (unsigned int)tmp[4] | ((unsigned int)tmp[5] << 16);
    u.w = (unsigned int)tmp[6] | ((unsigned int)tmp[7] << 16);
    *(uint4*)(Wb + (size_t)idx * 8) = u;
}

// ---------------- SpMM (bf16): Tout = L*Tin  or  2*L*Tin - Tsub ----------------
// one wave per vertex; scalar edge stream (8-padded), 8 independent row-gathers
// in flight per batch. All lanes gather the SAME row (uniform c) -> coalesced 512B.

__global__ __launch_bounds__(256) void spmm_kernel(const int* __restrict__ rp,
                                                   const int2* __restrict__ ev,
                                                   const unsigned short* __restrict__ Tin,
                                                   const unsigned short* __restrict__ Tsub,
                                                   unsigned short* __restrict__ Tout, int cheb) {
    int w = threadIdx.x >> 6;
    int l = threadIdx.x & 63;
    int m = blockIdx.x * 4 + w;
    int col = l * 4;
    int s = __builtin_amdgcn_readfirstlane(rp[m]);
    int e = __builtin_amdgcn_readfirstlane(rp[m + 1]);
    float a0 = 0.f, a1 = 0.f, a2 = 0.f, a3 = 0.f;
    for (int j = s; j < e; j += 8) {
        int2 ed[8];
        uint2 t[8];
#pragma unroll
        for (int i = 0; i < 8; ++i) ed[i] = ev[j + i];
#pragma unroll
        for (int i = 0; i < 8; ++i)
            t[i] = *(const uint2*)(Tin + (size_t)ed[i].x * ROWLEN + col);
#pragma unroll
        for (int i = 0; i < 8; ++i) {
            float v = __builtin_bit_cast(float, ed[i].y);
            a0 += v * bfl(t[i].x); a1 += v * bfh(t[i].x);
            a2 += v * bfl(t[i].y); a3 += v * bfh(t[i].y);
        }
    }
    if (cheb) {
        uint2 o = *(const uint2*)(Tsub + (size_t)m * ROWLEN + col);
        a0 = 2.f * a0 - bfl(o.x); a1 = 2.f * a1 - bfh(o.x);
        a2 = 2.f * a2 - bfl(o.y); a3 = 2.f * a3 - bfh(o.y);
    }
    uint2 r;
    r.x = pk(a0, a1); r.y = pk(a2, a3);
    *(uint2*)(Tout + (size_t)m * ROWLEN + col) = r;
}

// ---------------- final GEMM: out[n,m,f] = bias[f] + sum_k T_k[m, n*32+:] @ W_k ----------------
// MFMA 16x16x32 bf16; A straight from global (8 contiguous bf16/lane); n split
// across blocks for occupancy (grid = M/64 * 8).

__global__ __launch_bounds__(256) void gemm_kernel(const unsigned short* __restrict__ T0,
                                                   const unsigned short* __restrict__ T1,
                                                   const unsigned short* __restrict__ T2,
                                                   const unsigned short* __restrict__ T3,
                                                   const unsigned short* __restrict__ T4,
                                                   const unsigned short* __restrict__ Wb,
                                                   const float* __restrict__ bias,
                                                   float* __restrict__ out) {
    int w = threadIdx.x >> 6;
    int l = threadIdx.x & 63;
    int n  = blockIdx.x & 7;
    int mb = blockIdx.x >> 3;
    int m0 = (mb * 4 + w) * 16;
    int lrow = l & 15;           // A's m-offset AND C's column f
    int quad = l >> 4;

    short8 bfrag[5][2];
#pragma unroll
    for (int kf = 0; kf < 10; ++kf)
        bfrag[kf >> 1][kf & 1] = *(const short8*)(Wb + ((size_t)kf * 64 + l) * 8);

    float b0 = bias[lrow];
    float b1 = bias[16 + lrow];

    const unsigned short* Ts[5] = {T0, T1, T2, T3, T4};
    size_t abase = (size_t)(m0 + lrow) * ROWLEN + quad * 8 + n * FIN;

    f32x4 c0 = {0.f, 0.f, 0.f, 0.f};
    f32x4 c1 = {0.f, 0.f, 0.f, 0.f};
#pragma unroll
    for (int k = 0; k < 5; ++k) {
        short8 a = *(const short8*)(Ts[k] + abase);
        c0 = __builtin_amdgcn_mfma_f32_16x16x32_bf16(a, bfrag[k][0], c0, 0, 0, 0);
        c1 = __builtin_amdgcn_mfma_f32_16x16x32_bf16(a, bfrag[k][1], c1, 0, 0, 0);
    }
    float* op = out + ((size_t)n * M_VERT + m0) * FILT;
#pragma unroll
    for (int r = 0; r < 4; ++r) {
        int orow = quad * 4 + r;
        op[(size_t)orow * FILT + lrow]      = c0[r] + b0;
        op[(size_t)orow * FILT + 16 + lrow] = c1[r] + b1;
    }
}

// ---------------- launch ----------------

extern "C" void kernel_launch(void* const* d_in, const int* in_sizes, int n_in,
                              void* d_out, int out_size, void* d_ws, size_t ws_size,
                              hipStream_t stream) {
    const float* x    = (const float*)d_in[0];
    const float* vals = (const float*)d_in[1];
    const float* W    = (const float*)d_in[2];
    const float* bias = (const float*)d_in[3];
    const int*   rows = (const int*)d_in[4];
    const int*   cols = (const int*)d_in[5];
    float* out = (float*)d_out;

    // workspace: 5 bf16 T buffers (16 MiB each) + CSR (padded ev) + Wb (~88 MiB)
    const size_t TSZ = (size_t)M_VERT * ROWLEN;
    unsigned short* T0 = (unsigned short*)d_ws;
    unsigned short* T1 = T0 + TSZ;
    unsigned short* T2 = T1 + TSZ;
    unsigned short* T3 = T2 + TSZ;
    unsigned short* T4 = T3 + TSZ;
    int*  rp   = (int*)(T4 + TSZ);
    int*  fill = rp + (M_VERT + 2);
    int2* ev   = (int2*)(fill + M_VERT);
    unsigned short* Wb = (unsigned short*)(ev + EPAD);

    hipMemsetAsync(fill, 0, M_VERT * sizeof(int), stream);
    hipMemsetAsync(ev, 0, (size_t)EPAD * sizeof(int2), stream);   // pad edges: col 0, val 0.0
    hist_kernel<<<E_NNZ / 256, 256, 0, stream>>>(rows, fill);
    scan_kernel<<<1, 1024, 0, stream>>>(fill, rp, fill);
    scatter_kernel<<<E_NNZ / 256, 256, 0, stream>>>(rows, cols, vals, rp, fill, ev);
    packw_kernel<<<3, 256, 0, stream>>>(W, Wb);
    pack_kernel<<<M_VERT * 32 / 256, 256, 0, stream>>>(x, T0);

    // Chebyshev recurrence, all T_k kept (bf16)
    spmm_kernel<<<M_VERT / 4, 256, 0, stream>>>(rp, ev, T0, T0, T1, 0);
    spmm_kernel<<<M_VERT / 4, 256, 0, stream>>>(rp, ev, T1, T0, T2, 1);
    spmm_kernel<<<M_VERT / 4, 256, 0, stream>>>(rp, ev, T2, T1, T3, 1);
    spmm_kernel<<<M_VERT / 4, 256, 0, stream>>>(rp, ev, T3, T2, T4, 1);

    // single fused epilogue GEMM
    gemm_kernel<<<(M_VERT / 64) * 8, 256, 0, stream>>>(T0, T1, T2, T3, T4, Wb, bias, out);
}